// Round 1
// baseline (631.697 us; speedup 1.0000x reference)
//
#include <hip/hip_runtime.h>

#define BB 16
#define NN 2048
#define DD 128

typedef __attribute__((ext_vector_type(8))) __bf16 bf16x8;
typedef __attribute__((ext_vector_type(4))) float f32x4;

static __device__ __forceinline__ unsigned short f2b(float f) {
  union { float f; unsigned int u; } c; c.f = f;
  unsigned int u = c.u;
  unsigned int r = (u + 0x7FFFu + ((u >> 16) & 1u)) >> 16;
  return (unsigned short)r;
}

// X fp32 -> bf16 (row-major [b][i][d], same layout)
__global__ void k_cvt(const float* __restrict__ x, unsigned short* __restrict__ o) {
  int idx = blockIdx.x * 256 + threadIdx.x;
  float4 v = ((const float4*)x)[idx];
  ushort4 r;
  r.x = f2b(v.x); r.y = f2b(v.y); r.z = f2b(v.z); r.w = f2b(v.w);
  ((ushort4*)o)[idx] = r;
}

// adjT[b][j][i] = bf16(adj[b][i][j])  -- once; adj is layer-invariant
__global__ void k_transpose(const float* __restrict__ adj, unsigned short* __restrict__ adjT) {
  __shared__ float t[64][65];
  int b = blockIdx.z, j0 = blockIdx.x * 64, i0 = blockIdx.y * 64;
  int tid = threadIdx.x;
  const float* src = adj + (size_t)b * NN * NN;
  for (int p = 0; p < 16; ++p) {
    int idx = p * 256 + tid;
    int i = idx >> 6, j = idx & 63;
    t[j][i] = src[(size_t)(i0 + i) * NN + (j0 + j)];
  }
  __syncthreads();
  unsigned short* dst = adjT + (size_t)b * NN * NN;
  for (int p = 0; p < 4; ++p) {
    int idx = p * 256 + tid;
    int j = idx >> 4, i4 = (idx & 15) * 4;
    ushort4 r;
    r.x = f2b(t[j][i4 + 0]); r.y = f2b(t[j][i4 + 1]);
    r.z = f2b(t[j][i4 + 2]); r.w = f2b(t[j][i4 + 3]);
    *(ushort4*)(dst + (size_t)(j0 + j) * NN + (i0 + i4)) = r;
  }
}

// hwT[b][e][i] = sum_d W[d][e] * h[i][d]   (i.e. (h@W) transposed)
// MFMA: A[m=e][k=d] = W^T staged in LDS (padded rows), B[k=d][n=i] = h rows from global.
__global__ __launch_bounds__(256) void k_gemm1(const unsigned short* __restrict__ hb,
                                               const float* __restrict__ W,
                                               unsigned short* __restrict__ hwT) {
  __shared__ unsigned short sW[128 * 136];  // W^T, row stride 136 (pad 8) -> 2-way max
  int tid = threadIdx.x;
  int lane = tid & 63, w = tid >> 6;
  int q = lane >> 4, m = lane & 15;
  int b = blockIdx.y, i0 = blockIdx.x * 64;
  for (int p = 0; p < 64; ++p) {
    int idx = p * 256 + tid;
    int d = idx >> 7, e = idx & 127;
    sW[e * 136 + d] = f2b(W[idx]);
  }
  __syncthreads();
  f32x4 acc[8];
  for (int t = 0; t < 8; ++t)
    for (int r = 0; r < 4; ++r) acc[t][r] = 0.f;
  int irow = i0 + w * 16 + m;  // wave w covers i in [i0+16w, i0+16w+16)
  const unsigned short* hrow = hb + ((size_t)b * NN + irow) * DD;
  for (int kk = 0; kk < 4; ++kk) {
    int d0 = kk * 32 + q * 8;
    bf16x8 bf = *(const bf16x8*)(hrow + d0);  // B-frag: contiguous d of row i
    for (int mt = 0; mt < 8; ++mt) {
      bf16x8 af = *(const bf16x8*)(sW + (mt * 16 + m) * 136 + d0);
      acc[mt] = __builtin_amdgcn_mfma_f32_16x16x32_bf16(af, bf, acc[mt], 0, 0, 0);
    }
  }
  unsigned short* dst = hwT + (size_t)b * DD * NN;
  for (int mt = 0; mt < 8; ++mt)
    for (int r = 0; r < 4; ++r)
      dst[(size_t)(mt * 16 + q * 4 + r) * NN + irow] = f2b(acc[mt][r]);
}

// agg[j][e] = sum_i adjT[j][i]*hwT[e][i]; fused +bias +res, LayerNorm over e, ReLU.
// Block: 64 j x 128 e, 2 waves (wave-tile 64x64), BK=64. LDS rows padded +8 bf16.
__global__ __launch_bounds__(128) void k_gemm2(const unsigned short* __restrict__ adjT,
                                               const unsigned short* __restrict__ hwT,
                                               const float* __restrict__ res,
                                               const float* __restrict__ bias,
                                               const float* __restrict__ gamma,
                                               const float* __restrict__ beta,
                                               float* __restrict__ outf,
                                               unsigned short* __restrict__ outb) {
  __shared__ union {
    struct { unsigned short a[64 * 72]; unsigned short h[128 * 72]; } s;
    float z[64 * 132];  // epilogue z-tile aliases staging buffers
  } u;
  __shared__ float smu[64], srs[64];
  int tid = threadIdx.x;
  int lane = tid & 63, w = tid >> 6;  // w in {0,1}
  int q = lane >> 4, m = lane & 15;
  int b = blockIdx.y, j0 = blockIdx.x * 64;
  const unsigned short* At = adjT + (size_t)b * NN * NN;
  const unsigned short* Ht = hwT + (size_t)b * DD * NN;
  f32x4 acc[4][4];
  for (int i = 0; i < 4; ++i)
    for (int j = 0; j < 4; ++j)
      for (int r = 0; r < 4; ++r) acc[i][j][r] = 0.f;
  for (int k0 = 0; k0 < NN; k0 += 64) {
    __syncthreads();
    for (int p = 0; p < 4; ++p) {  // stage adjT tile: 64 rows x 64 i
      int c = p * 128 + tid;
      int j = c >> 3, i8 = (c & 7) * 8;
      *(bf16x8*)(u.s.a + j * 72 + i8) =
          *(const bf16x8*)(At + (size_t)(j0 + j) * NN + k0 + i8);
    }
    for (int p = 0; p < 8; ++p) {  // stage hwT tile: 128 rows x 64 i
      int c = p * 128 + tid;
      int e = c >> 3, i8 = (c & 7) * 8;
      *(bf16x8*)(u.s.h + e * 72 + i8) =
          *(const bf16x8*)(Ht + (size_t)e * NN + k0 + i8);
    }
    __syncthreads();
    for (int kk = 0; kk < 2; ++kk) {
      int dk = kk * 32 + q * 8;
      bf16x8 bfr[4];
      for (int nt = 0; nt < 4; ++nt)
        bfr[nt] = *(const bf16x8*)(u.s.h + (w * 64 + nt * 16 + m) * 72 + dk);
      for (int mt = 0; mt < 4; ++mt) {
        bf16x8 af = *(const bf16x8*)(u.s.a + (mt * 16 + m) * 72 + dk);
        for (int nt = 0; nt < 4; ++nt)
          acc[mt][nt] = __builtin_amdgcn_mfma_f32_16x16x32_bf16(af, bfr[nt], acc[mt][nt], 0, 0, 0);
      }
    }
  }
  __syncthreads();
  // z = agg + bias + residual  (C/D layout: col=lane&15 -> e, row=q*4+reg -> j)
  const float* resb = res + (size_t)b * NN * DD;
  for (int mt = 0; mt < 4; ++mt)
    for (int nt = 0; nt < 4; ++nt)
      for (int r = 0; r < 4; ++r) {
        int j = mt * 16 + q * 4 + r;
        int e = w * 64 + nt * 16 + m;
        u.z[j * 132 + e] = acc[mt][nt][r] + bias[e] + resb[(size_t)(j0 + j) * DD + e];
      }
  __syncthreads();
  {  // LN stats: 2 threads per row, shfl-combine
    int j = tid >> 1, s = tid & 1;
    float sum = 0.f, sq = 0.f;
    for (int k = 0; k < 64; ++k) {
      float v = u.z[j * 132 + s * 64 + k];
      sum += v; sq += v * v;
    }
    sum += __shfl_xor(sum, 1);
    sq += __shfl_xor(sq, 1);
    if (s == 0) {
      float mu = sum * (1.f / 128.f);
      float var = sq * (1.f / 128.f) - mu * mu;
      smu[j] = mu;
      srs[j] = rsqrtf(var + 1e-5f);
    }
  }
  __syncthreads();
  float* ob = outf + (size_t)b * NN * DD;
  unsigned short* bb = outb + (size_t)b * NN * DD;
  for (int p = 0; p < 64; ++p) {
    float v = (u.z[p * 132 + tid] - smu[p]) * srs[p] * gamma[tid] + beta[tid];
    v = fmaxf(v, 0.f);
    size_t off = (size_t)(j0 + p) * DD + tid;
    ob[off] = v;      // fp32 h (residual for next layer / final output)
    bb[off] = f2b(v); // bf16 h (next layer's GEMM1 input)
  }
}

extern "C" void kernel_launch(void* const* d_in, const int* in_sizes, int n_in,
                              void* d_out, int out_size, void* d_ws, size_t ws_size,
                              hipStream_t stream) {
  const float* X   = (const float*)d_in[0];
  const float* adj = (const float*)d_in[1];
  const float* Ws  = (const float*)d_in[2];
  const float* bs  = (const float*)d_in[3];
  const float* gms = (const float*)d_in[4];
  const float* bts = (const float*)d_in[5];
  float* out = (float*)d_out;

  // ws layout (needs ~151 MB): adjT bf16 | hwT bf16 | h bf16
  unsigned short* adjT = (unsigned short*)d_ws;           // BB*NN*NN
  unsigned short* hwT  = adjT + (size_t)BB * NN * NN;     // BB*DD*NN
  unsigned short* hb   = hwT + (size_t)BB * DD * NN;      // BB*NN*DD

  k_cvt<<<dim3(4096), 256, 0, stream>>>(X, hb);
  k_transpose<<<dim3(NN / 64, NN / 64, BB), 256, 0, stream>>>(adj, adjT);
  for (int l = 0; l < 3; ++l) {
    k_gemm1<<<dim3(NN / 64, BB), 256, 0, stream>>>(hb, Ws + (size_t)l * DD * DD, hwT);
    const float* res = (l == 0) ? X : (const float*)out;
    k_gemm2<<<dim3(NN / 64, BB), 128, 0, stream>>>(adjT, hwT, res, bs + l * DD,
                                                   gms + l * DD, bts + l * DD, out, hb);
  }
}

// Round 2
// 592.545 us; speedup vs baseline: 1.0661x; 1.0661x over previous
//
#include <hip/hip_runtime.h>

#define BB 16
#define NN 2048
#define DD 128
#define KS 4
#define KC (NN / KS)

typedef __attribute__((ext_vector_type(8))) __bf16 bf16x8;
typedef __attribute__((ext_vector_type(4))) float f32x4;
typedef __attribute__((address_space(3))) unsigned int lds_u32;
typedef __attribute__((address_space(1))) const unsigned int glob_u32;

static __device__ __forceinline__ unsigned short f2b(float f) {
  union { float f; unsigned int u; } c; c.f = f;
  unsigned int u = c.u;
  unsigned int r = (u + 0x7FFFu + ((u >> 16) & 1u)) >> 16;
  return (unsigned short)r;
}

// X fp32 -> bf16 (row-major [b][i][d], same layout)
__global__ void k_cvt(const float* __restrict__ x, unsigned short* __restrict__ o) {
  int idx = blockIdx.x * 256 + threadIdx.x;
  float4 v = ((const float4*)x)[idx];
  ushort4 r;
  r.x = f2b(v.x); r.y = f2b(v.y); r.z = f2b(v.z); r.w = f2b(v.w);
  ((ushort4*)o)[idx] = r;
}

// adjT[b][j][i] = bf16(adj[b][i][j])  -- once; adj is layer-invariant
__global__ void k_transpose(const float* __restrict__ adj, unsigned short* __restrict__ adjT) {
  __shared__ float t[64][65];
  int b = blockIdx.z, j0 = blockIdx.x * 64, i0 = blockIdx.y * 64;
  int tid = threadIdx.x;
  const float* src = adj + (size_t)b * NN * NN;
  for (int p = 0; p < 16; ++p) {
    int idx = p * 256 + tid;
    int i = idx >> 6, j = idx & 63;
    t[j][i] = src[(size_t)(i0 + i) * NN + (j0 + j)];
  }
  __syncthreads();
  unsigned short* dst = adjT + (size_t)b * NN * NN;
  for (int p = 0; p < 4; ++p) {
    int idx = p * 256 + tid;
    int j = idx >> 4, i4 = (idx & 15) * 4;
    ushort4 r;
    r.x = f2b(t[j][i4 + 0]); r.y = f2b(t[j][i4 + 1]);
    r.z = f2b(t[j][i4 + 2]); r.w = f2b(t[j][i4 + 3]);
    *(ushort4*)(dst + (size_t)(j0 + j) * NN + (i0 + i4)) = r;
  }
}

// hwT[b][e][i] = sum_d W[d][e] * h[i][d]   (i.e. (h@W) transposed)
__global__ __launch_bounds__(256) void k_gemm1(const unsigned short* __restrict__ hb,
                                               const float* __restrict__ W,
                                               unsigned short* __restrict__ hwT) {
  __shared__ unsigned short sW[128 * 136];  // W^T, row stride 136 (pad 8)
  int tid = threadIdx.x;
  int lane = tid & 63, w = tid >> 6;
  int q = lane >> 4, m = lane & 15;
  int b = blockIdx.y, i0 = blockIdx.x * 64;
  for (int p = 0; p < 64; ++p) {
    int idx = p * 256 + tid;
    int d = idx >> 7, e = idx & 127;
    sW[e * 136 + d] = f2b(W[idx]);
  }
  __syncthreads();
  f32x4 acc[8];
  for (int t = 0; t < 8; ++t)
    for (int r = 0; r < 4; ++r) acc[t][r] = 0.f;
  int irow = i0 + w * 16 + m;
  const unsigned short* hrow = hb + ((size_t)b * NN + irow) * DD;
  for (int kk = 0; kk < 4; ++kk) {
    int d0 = kk * 32 + q * 8;
    bf16x8 bf = *(const bf16x8*)(hrow + d0);
    for (int mt = 0; mt < 8; ++mt) {
      bf16x8 af = *(const bf16x8*)(sW + (mt * 16 + m) * 136 + d0);
      acc[mt] = __builtin_amdgcn_mfma_f32_16x16x32_bf16(af, bf, acc[mt], 0, 0, 0);
    }
  }
  unsigned short* dst = hwT + (size_t)b * DD * NN;
  for (int mt = 0; mt < 8; ++mt)
    for (int r = 0; r < 4; ++r)
      dst[(size_t)(mt * 16 + q * 4 + r) * NN + irow] = f2b(acc[mt][r]);
}

// pacc[ks][b][j][e] = sum_{i in ks-chunk} adjT[j][i]*hwT[e][i]
// 256 thr / 4 waves, 128x128 tile, wave-tile 64x64, BK=64,
// global_load_lds(16B) staging with XOR chunk swizzle (no padding needed).
__global__ __launch_bounds__(256) void k_gemm2(const unsigned short* __restrict__ adjT,
                                               const unsigned short* __restrict__ hwT,
                                               float* __restrict__ pacc) {
  __shared__ __align__(16) unsigned short sA[128 * 64];
  __shared__ __align__(16) unsigned short sH[128 * 64];
  int tid = threadIdx.x;
  int lane = tid & 63, w = tid >> 6;
  int q = lane >> 4, m = lane & 15;
  int wj = w & 1, we = w >> 1;
  int b = blockIdx.y, j0 = blockIdx.x * 128, ks = blockIdx.z;
  const unsigned short* At = adjT + (size_t)b * NN * NN;
  const unsigned short* Ht = hwT + (size_t)b * DD * NN;

  // per-lane loop-invariant staging source pointers (advance 64 elems/iter)
  const unsigned short* aSrc[4];
  const unsigned short* hSrc[4];
#pragma unroll
  for (int it = 0; it < 4; ++it) {
    int p = (w * 4 + it) * 64 + lane;
    int r = p >> 3, cg = (p & 7) ^ (r & 7);
    aSrc[it] = At + (size_t)(j0 + r) * NN + ks * KC + cg * 8;
    hSrc[it] = Ht + (size_t)r * NN + ks * KC + cg * 8;
  }

  f32x4 acc[4][4];
#pragma unroll
  for (int i = 0; i < 4; ++i)
#pragma unroll
    for (int j = 0; j < 4; ++j)
#pragma unroll
      for (int r = 0; r < 4; ++r) acc[i][j][r] = 0.f;

  for (int k0 = 0; k0 < KC; k0 += 64) {
    __syncthreads();
#pragma unroll
    for (int it = 0; it < 4; ++it) {
      __builtin_amdgcn_global_load_lds((glob_u32*)aSrc[it],
                                       (lds_u32*)(sA + (w * 4 + it) * 512), 16, 0, 0);
      __builtin_amdgcn_global_load_lds((glob_u32*)hSrc[it],
                                       (lds_u32*)(sH + (w * 4 + it) * 512), 16, 0, 0);
      aSrc[it] += 64; hSrc[it] += 64;
    }
    __syncthreads();
#pragma unroll
    for (int kk = 0; kk < 2; ++kk) {
      bf16x8 af[4], bf[4];
#pragma unroll
      for (int mt = 0; mt < 4; ++mt) {
        int r = wj * 64 + mt * 16 + m;
        int c = (kk * 4 + q) ^ (r & 7);
        af[mt] = *(const bf16x8*)(sA + r * 64 + c * 8);
      }
#pragma unroll
      for (int nt = 0; nt < 4; ++nt) {
        int r = we * 64 + nt * 16 + m;
        int c = (kk * 4 + q) ^ (r & 7);
        bf[nt] = *(const bf16x8*)(sH + r * 64 + c * 8);
      }
#pragma unroll
      for (int mt = 0; mt < 4; ++mt)
#pragma unroll
        for (int nt = 0; nt < 4; ++nt)
          acc[mt][nt] = __builtin_amdgcn_mfma_f32_16x16x32_bf16(af[mt], bf[nt], acc[mt][nt], 0, 0, 0);
    }
  }
  float* P = pacc + ((size_t)ks * BB + b) * (size_t)NN * DD + (size_t)j0 * DD;
#pragma unroll
  for (int mt = 0; mt < 4; ++mt)
#pragma unroll
    for (int nt = 0; nt < 4; ++nt)
#pragma unroll
      for (int r = 0; r < 4; ++r)
        P[(size_t)(wj * 64 + mt * 16 + q * 4 + r) * DD + we * 64 + nt * 16 + m] = acc[mt][nt][r];
}

// sum KS partials + bias + residual, LayerNorm over e, ReLU -> out fp32 + hb bf16
__global__ __launch_bounds__(256) void k_reduce(const float* __restrict__ pacc,
                                                const float* __restrict__ res,
                                                const float* __restrict__ bias,
                                                const float* __restrict__ gamma,
                                                const float* __restrict__ beta,
                                                float* __restrict__ outf,
                                                unsigned short* __restrict__ outb) {
  __shared__ float z[64 * 132];
  __shared__ float smu[64], srs[64];
  int tid = threadIdx.x;
  int b = blockIdx.y, j0 = blockIdx.x * 64;
  size_t base = ((size_t)b * NN + j0) * DD;
  const float4* p0 = (const float4*)(pacc + base);
  const float4* p1 = (const float4*)(pacc + (size_t)1 * BB * NN * DD + base);
  const float4* p2 = (const float4*)(pacc + (size_t)2 * BB * NN * DD + base);
  const float4* p3 = (const float4*)(pacc + (size_t)3 * BB * NN * DD + base);
  const float4* r4 = (const float4*)(res + base);
  float4 bi = ((const float4*)bias)[tid & 31];
#pragma unroll
  for (int p = 0; p < 8; ++p) {
    int idx = p * 256 + tid;       // float4 index in 64x128/4
    int j = idx >> 5, e4 = idx & 31;
    float4 a0 = p0[idx], a1 = p1[idx], a2 = p2[idx], a3 = p3[idx], rr = r4[idx];
    float4 v;
    v.x = a0.x + a1.x + a2.x + a3.x + rr.x + bi.x;
    v.y = a0.y + a1.y + a2.y + a3.y + rr.y + bi.y;
    v.z = a0.z + a1.z + a2.z + a3.z + rr.z + bi.z;
    v.w = a0.w + a1.w + a2.w + a3.w + rr.w + bi.w;
    *(float4*)&z[j * 132 + e4 * 4] = v;
  }
  __syncthreads();
  {
    int j = tid >> 2, s = tid & 3;
    float sum = 0.f, sq = 0.f;
#pragma unroll
    for (int k = 0; k < 32; ++k) {
      float v = z[j * 132 + s * 32 + k];
      sum += v; sq += v * v;
    }
    sum += __shfl_xor(sum, 1); sq += __shfl_xor(sq, 1);
    sum += __shfl_xor(sum, 2); sq += __shfl_xor(sq, 2);
    if (s == 0) {
      float mu = sum * (1.f / 128.f);
      float var = sq * (1.f / 128.f) - mu * mu;
      smu[j] = mu;
      srs[j] = rsqrtf(var + 1e-5f);
    }
  }
  __syncthreads();
  int e = tid & 127;
  float g = gamma[e], bt = beta[e];
#pragma unroll
  for (int p = 0; p < 32; ++p) {
    int idx = p * 256 + tid;
    int j = idx >> 7;
    float v = (z[j * 132 + e] - smu[j]) * srs[j] * g + bt;
    v = fmaxf(v, 0.f);
    outf[base + idx] = v;
    outb[base + idx] = f2b(v);
  }
}

extern "C" void kernel_launch(void* const* d_in, const int* in_sizes, int n_in,
                              void* d_out, int out_size, void* d_ws, size_t ws_size,
                              hipStream_t stream) {
  const float* X   = (const float*)d_in[0];
  const float* adj = (const float*)d_in[1];
  const float* Ws  = (const float*)d_in[2];
  const float* bs  = (const float*)d_in[3];
  const float* gms = (const float*)d_in[4];
  const float* bts = (const float*)d_in[5];
  float* out = (float*)d_out;

  // ws: adjT bf16 (134MB) | hwT bf16 (8MB) | hb bf16 (8MB) | pacc fp32 (67MB)
  unsigned short* adjT = (unsigned short*)d_ws;
  unsigned short* hwT  = adjT + (size_t)BB * NN * NN;
  unsigned short* hb   = hwT + (size_t)BB * DD * NN;
  float* pacc = (float*)(hb + (size_t)BB * NN * DD);

  k_cvt<<<dim3(4096), 256, 0, stream>>>(X, hb);
  k_transpose<<<dim3(NN / 64, NN / 64, BB), 256, 0, stream>>>(adj, adjT);
  for (int l = 0; l < 3; ++l) {
    k_gemm1<<<dim3(NN / 64, BB), 256, 0, stream>>>(hb, Ws + (size_t)l * DD * DD, hwT);
    k_gemm2<<<dim3(NN / 128, BB, KS), 256, 0, stream>>>(adjT, hwT, pacc);
    const float* res = (l == 0) ? X : (const float*)out;
    k_reduce<<<dim3(NN / 64, BB), 256, 0, stream>>>(pacc, res, bs + l * DD,
                                                    gms + l * DD, bts + l * DD, out, hb);
  }
}

// Round 3
// 560.166 us; speedup vs baseline: 1.1277x; 1.0578x over previous
//
#include <hip/hip_runtime.h>

#define BB 16
#define NN 2048
#define DD 128
#define KS 4
#define KC (NN / KS)

typedef __attribute__((ext_vector_type(8))) __bf16 bf16x8;
typedef __attribute__((ext_vector_type(4))) float f32x4;
typedef __attribute__((ext_vector_type(4))) unsigned int u32x4;
typedef __attribute__((address_space(3))) unsigned int lds_u32;
typedef __attribute__((address_space(1))) const unsigned int glob_u32;

static __device__ __forceinline__ unsigned short f2b(float f) {
  union { float f; unsigned int u; } c; c.f = f;
  unsigned int u = c.u;
  unsigned int r = (u + 0x7FFFu + ((u >> 16) & 1u)) >> 16;
  return (unsigned short)r;
}
static __device__ __forceinline__ float b2f(unsigned short u) {
  union { unsigned int u; float f; } c; c.u = ((unsigned int)u) << 16;
  return c.f;
}

// adjT[b][j][i] = bf16(adj[b][i][j])  -- once; adj is layer-invariant
__global__ void k_transpose(const float* __restrict__ adj, unsigned short* __restrict__ adjT) {
  __shared__ float t[64][65];
  int b = blockIdx.z, j0 = blockIdx.x * 64, i0 = blockIdx.y * 64;
  int tid = threadIdx.x;
  const float* src = adj + (size_t)b * NN * NN;
  for (int p = 0; p < 16; ++p) {
    int idx = p * 256 + tid;
    int i = idx >> 6, j = idx & 63;
    t[j][i] = src[(size_t)(i0 + i) * NN + (j0 + j)];
  }
  __syncthreads();
  unsigned short* dst = adjT + (size_t)b * NN * NN;
  for (int p = 0; p < 4; ++p) {
    int idx = p * 256 + tid;
    int j = idx >> 4, i4 = (idx & 15) * 4;
    ushort4 r;
    r.x = f2b(t[j][i4 + 0]); r.y = f2b(t[j][i4 + 1]);
    r.z = f2b(t[j][i4 + 2]); r.w = f2b(t[j][i4 + 3]);
    *(ushort4*)(dst + (size_t)(j0 + j) * NN + (i0 + i4)) = r;
  }
}

// layer-0 gemm1: hwT[b][e][i] = sum_d W0[d][e] * X[b][i][d]  (reads fp32 X, cvt inline)
__global__ __launch_bounds__(256) void k_g1x(const float* __restrict__ X,
                                             const float* __restrict__ W,
                                             unsigned short* __restrict__ hwT) {
  __shared__ unsigned short sW[128 * 136];
  int tid = threadIdx.x;
  int lane = tid & 63, w = tid >> 6;
  int q = lane >> 4, m = lane & 15;
  int b = blockIdx.y, i0 = blockIdx.x * 64;
  for (int p = 0; p < 64; ++p) {
    int idx = p * 256 + tid;
    int d = idx >> 7, e = idx & 127;
    sW[e * 136 + d] = f2b(W[idx]);
  }
  __syncthreads();
  f32x4 acc[8];
  for (int t = 0; t < 8; ++t)
    for (int r = 0; r < 4; ++r) acc[t][r] = 0.f;
  int irow = i0 + w * 16 + m;
  const float* hrow = X + ((size_t)b * NN + irow) * DD;
  for (int kk = 0; kk < 4; ++kk) {
    int d0 = kk * 32 + q * 8;
    float4 h0 = *(const float4*)(hrow + d0);
    float4 h1 = *(const float4*)(hrow + d0 + 4);
    union { bf16x8 v; unsigned short s[8]; } ub;
    ub.s[0] = f2b(h0.x); ub.s[1] = f2b(h0.y); ub.s[2] = f2b(h0.z); ub.s[3] = f2b(h0.w);
    ub.s[4] = f2b(h1.x); ub.s[5] = f2b(h1.y); ub.s[6] = f2b(h1.z); ub.s[7] = f2b(h1.w);
    for (int mt = 0; mt < 8; ++mt) {
      bf16x8 af = *(const bf16x8*)(sW + (mt * 16 + m) * 136 + d0);
      acc[mt] = __builtin_amdgcn_mfma_f32_16x16x32_bf16(af, ub.v, acc[mt], 0, 0, 0);
    }
  }
  unsigned short* dst = hwT + (size_t)b * DD * NN;
  for (int mt = 0; mt < 8; ++mt)
    for (int r = 0; r < 4; ++r)
      dst[(size_t)(mt * 16 + q * 4 + r) * NN + irow] = f2b(acc[mt][r]);
}

// pacc[ks][b][j][e] (bf16) = sum_{i in ks-chunk} adjT[j][i]*hwT[e][i]
// 256 thr / 4 waves, 128x128 tile, BK=64, global_load_lds(16B) + XOR swizzle staging,
// epilogue: acc -> LDS bounce -> fully-coalesced 16B bf16 stores.
__global__ __launch_bounds__(256) void k_gemm2(const unsigned short* __restrict__ adjT,
                                               const unsigned short* __restrict__ hwT,
                                               unsigned short* __restrict__ pacc) {
  __shared__ __align__(16) unsigned short sAB[16384];  // sA | sH, also epilogue 128x128 bounce
  unsigned short* sA = sAB;
  unsigned short* sH = sAB + 8192;
  int tid = threadIdx.x;
  int lane = tid & 63, w = tid >> 6;
  int q = lane >> 4, m = lane & 15;
  int wj = w & 1, we = w >> 1;
  int b = blockIdx.y, j0 = blockIdx.x * 128, ks = blockIdx.z;
  const unsigned short* At = adjT + (size_t)b * NN * NN;
  const unsigned short* Ht = hwT + (size_t)b * DD * NN;

  const unsigned short* aSrc[4];
  const unsigned short* hSrc[4];
#pragma unroll
  for (int it = 0; it < 4; ++it) {
    int p = (w * 4 + it) * 64 + lane;
    int r = p >> 3, cg = (p & 7) ^ (r & 7);
    aSrc[it] = At + (size_t)(j0 + r) * NN + ks * KC + cg * 8;
    hSrc[it] = Ht + (size_t)r * NN + ks * KC + cg * 8;
  }

  f32x4 acc[4][4];
#pragma unroll
  for (int i = 0; i < 4; ++i)
#pragma unroll
    for (int j = 0; j < 4; ++j)
#pragma unroll
      for (int r = 0; r < 4; ++r) acc[i][j][r] = 0.f;

  for (int k0 = 0; k0 < KC; k0 += 64) {
    __syncthreads();
#pragma unroll
    for (int it = 0; it < 4; ++it) {
      __builtin_amdgcn_global_load_lds((glob_u32*)aSrc[it],
                                       (lds_u32*)(sA + (w * 4 + it) * 512), 16, 0, 0);
      __builtin_amdgcn_global_load_lds((glob_u32*)hSrc[it],
                                       (lds_u32*)(sH + (w * 4 + it) * 512), 16, 0, 0);
      aSrc[it] += 64; hSrc[it] += 64;
    }
    __syncthreads();
#pragma unroll
    for (int kk = 0; kk < 2; ++kk) {
      bf16x8 af[4], bf[4];
#pragma unroll
      for (int mt = 0; mt < 4; ++mt) {
        int r = wj * 64 + mt * 16 + m;
        int c = (kk * 4 + q) ^ (r & 7);
        af[mt] = *(const bf16x8*)(sA + r * 64 + c * 8);
      }
#pragma unroll
      for (int nt = 0; nt < 4; ++nt) {
        int r = we * 64 + nt * 16 + m;
        int c = (kk * 4 + q) ^ (r & 7);
        bf[nt] = *(const bf16x8*)(sH + r * 64 + c * 8);
      }
#pragma unroll
      for (int mt = 0; mt < 4; ++mt)
#pragma unroll
        for (int nt = 0; nt < 4; ++nt)
          acc[mt][nt] = __builtin_amdgcn_mfma_f32_16x16x32_bf16(af[mt], bf[nt], acc[mt][nt], 0, 0, 0);
    }
  }
  __syncthreads();
#pragma unroll
  for (int mt = 0; mt < 4; ++mt)
#pragma unroll
    for (int nt = 0; nt < 4; ++nt)
#pragma unroll
      for (int r = 0; r < 4; ++r) {
        int row = wj * 64 + mt * 16 + q * 4 + r;
        int col = we * 64 + nt * 16 + m;
        sAB[row * 128 + col] = f2b(acc[mt][nt][r]);
      }
  __syncthreads();
  unsigned short* P = pacc + ((size_t)ks * BB + b) * (size_t)NN * DD + (size_t)j0 * DD;
#pragma unroll
  for (int p = 0; p < 8; ++p) {
    int idx = p * 256 + tid;
    int row = idx >> 4, c8 = (idx & 15) * 8;
    *(u32x4*)(P + (size_t)row * DD + c8) = *(const u32x4*)(sAB + row * 128 + c8);
  }
}

// Fused: z = sum_ks pacc + bias + res; LN+ReLU -> out fp32 (+ z LDS);
// then (doW) next-layer gemm1 on the same 64 rows -> hwT.
__global__ __launch_bounds__(256) void k_rg1(const unsigned short* __restrict__ pacc,
                                             const float* __restrict__ res,
                                             const float* __restrict__ bias,
                                             const float* __restrict__ gamma,
                                             const float* __restrict__ beta,
                                             const float* __restrict__ W,
                                             float* __restrict__ outf,
                                             unsigned short* __restrict__ hwT,
                                             int doW) {
  __shared__ float z[64 * 132];
  __shared__ float smu[64], srs[64];
  __shared__ unsigned short sW[128 * 136];
  int tid = threadIdx.x;
  int lane = tid & 63, w = tid >> 6;
  int q = lane >> 4, m = lane & 15;
  int b = blockIdx.y, j0 = blockIdx.x * 64;
  if (doW) {
    for (int p = 0; p < 64; ++p) {
      int idx = p * 256 + tid;
      int d = idx >> 7, e = idx & 127;
      sW[e * 136 + d] = f2b(W[idx]);
    }
  }
  size_t base = ((size_t)b * NN + j0) * DD;
  const size_t kstride = (size_t)BB * NN * DD;
  const unsigned short* P = pacc + base;
#pragma unroll
  for (int p = 0; p < 4; ++p) {
    int idx = p * 256 + tid;       // 16B-chunk index in 64x128
    int j = idx >> 4, c8 = (idx & 15) * 8;
    size_t off = (size_t)j * DD + c8;
    float v[8];
    const float4* r4 = (const float4*)(res + base + off);
    float4 r0 = r4[0], r1 = r4[1];
    const float4* bi4 = (const float4*)(bias + c8);
    float4 b0 = bi4[0], b1 = bi4[1];
    v[0] = r0.x + b0.x; v[1] = r0.y + b0.y; v[2] = r0.z + b0.z; v[3] = r0.w + b0.w;
    v[4] = r1.x + b1.x; v[5] = r1.y + b1.y; v[6] = r1.z + b1.z; v[7] = r1.w + b1.w;
#pragma unroll
    for (int s = 0; s < KS; ++s) {
      union { u32x4 u; unsigned short h[8]; } up;
      up.u = *(const u32x4*)(P + s * kstride + off);
#pragma unroll
      for (int t = 0; t < 8; ++t) v[t] += b2f(up.h[t]);
    }
#pragma unroll
    for (int t = 0; t < 8; ++t) z[j * 132 + c8 + t] = v[t];
  }
  __syncthreads();
  {
    int j = tid >> 2, s = tid & 3;
    float sum = 0.f, sq = 0.f;
#pragma unroll
    for (int k = 0; k < 32; ++k) {
      float v = z[j * 132 + s * 32 + k];
      sum += v; sq += v * v;
    }
    sum += __shfl_xor(sum, 1); sq += __shfl_xor(sq, 1);
    sum += __shfl_xor(sum, 2); sq += __shfl_xor(sq, 2);
    if (s == 0) {
      float mu = sum * (1.f / 128.f);
      float var = sq * (1.f / 128.f) - mu * mu;
      smu[j] = mu;
      srs[j] = rsqrtf(var + 1e-5f);
    }
  }
  __syncthreads();
  {
    int e = tid & 127;
    float g = gamma[e], bt = beta[e];
#pragma unroll
    for (int p = 0; p < 32; ++p) {
      int idx = p * 256 + tid;
      int j = idx >> 7;
      float v = (z[j * 132 + e] - smu[j]) * srs[j] * g + bt;
      v = fmaxf(v, 0.f);
      outf[base + idx] = v;
      z[j * 132 + e] = v;   // h for phase-2 gemm1 (same thread, same slot: no race)
    }
  }
  if (!doW) return;
  __syncthreads();
  f32x4 acc[8];
#pragma unroll
  for (int t = 0; t < 8; ++t)
#pragma unroll
    for (int r = 0; r < 4; ++r) acc[t][r] = 0.f;
  int irow = j0 + w * 16 + m;
  const float* hrow = &z[(w * 16 + m) * 132];
#pragma unroll
  for (int kk = 0; kk < 4; ++kk) {
    int d0 = kk * 32 + q * 8;
    float4 h0 = *(const float4*)(hrow + d0);
    float4 h1 = *(const float4*)(hrow + d0 + 4);
    union { bf16x8 v; unsigned short s[8]; } ub;
    ub.s[0] = f2b(h0.x); ub.s[1] = f2b(h0.y); ub.s[2] = f2b(h0.z); ub.s[3] = f2b(h0.w);
    ub.s[4] = f2b(h1.x); ub.s[5] = f2b(h1.y); ub.s[6] = f2b(h1.z); ub.s[7] = f2b(h1.w);
#pragma unroll
    for (int mt = 0; mt < 8; ++mt) {
      bf16x8 af = *(const bf16x8*)(sW + (mt * 16 + m) * 136 + d0);
      acc[mt] = __builtin_amdgcn_mfma_f32_16x16x32_bf16(af, ub.v, acc[mt], 0, 0, 0);
    }
  }
  unsigned short* dst = hwT + (size_t)b * DD * NN;
#pragma unroll
  for (int mt = 0; mt < 8; ++mt)
#pragma unroll
    for (int r = 0; r < 4; ++r)
      dst[(size_t)(mt * 16 + q * 4 + r) * NN + irow] = f2b(acc[mt][r]);
}

extern "C" void kernel_launch(void* const* d_in, const int* in_sizes, int n_in,
                              void* d_out, int out_size, void* d_ws, size_t ws_size,
                              hipStream_t stream) {
  const float* X   = (const float*)d_in[0];
  const float* adj = (const float*)d_in[1];
  const float* Ws  = (const float*)d_in[2];
  const float* bs  = (const float*)d_in[3];
  const float* gms = (const float*)d_in[4];
  const float* bts = (const float*)d_in[5];
  float* out = (float*)d_out;

  // ws: adjT bf16 (134MB) | hwT bf16 (8.4MB) | pacc bf16 (33.6MB)
  unsigned short* adjT = (unsigned short*)d_ws;
  unsigned short* hwT  = adjT + (size_t)BB * NN * NN;
  unsigned short* pacc = hwT + (size_t)BB * DD * NN;

  k_g1x<<<dim3(NN / 64, BB), 256, 0, stream>>>(X, Ws, hwT);
  k_transpose<<<dim3(NN / 64, NN / 64, BB), 256, 0, stream>>>(adj, adjT);
  for (int l = 0; l < 3; ++l) {
    k_gemm2<<<dim3(NN / 128, BB, KS), 256, 0, stream>>>(adjT, hwT, pacc);
    const float* res = (l == 0) ? X : (const float*)out;
    const float* Wn = Ws + (size_t)((l < 2) ? (l + 1) : 0) * DD * DD;
    k_rg1<<<dim3(NN / 64, BB), 256, 0, stream>>>(pacc, res, bs + l * DD,
                                                 gms + l * DD, bts + l * DD,
                                                 Wn, out, hwT, (l < 2) ? 1 : 0);
  }
}